// Round 4
// baseline (317.525 us; speedup 1.0000x reference)
//
#include <hip/hip_runtime.h>
#include <cstdint>

#define BSZ   8192
#define NGT   8
#define ROW   90     // B*5 + C
#define CELLS 49     // 7*7
#define BLOCK 256
#define WPB   4      // waves per block
#define GRID  (BSZ / WPB)   // 2048 blocks, one batch item per wave
#define POISON 0xAAAAAAAAu  // harness re-poisons d_ws to 0xAA bytes every call

// Single fused kernel: wave-per-batch main computation + last-block-done
// final reduction. d_ws layout: [0..GRID) float partials, [GRID] uint32
// arrival counter (starts at POISON each call — harness guarantee).
__launch_bounds__(BLOCK, 8)
__global__ void yolo_fused(const float* __restrict__ preds,
                           const float* __restrict__ gtb,
                           const int*   __restrict__ gtl,
                           float* __restrict__ partial,
                           unsigned int* __restrict__ counter,
                           float* __restrict__ out)
{
    __shared__ float s_red[WPB];
    __shared__ int   s_last;
    const int tid  = threadIdx.x;
    const int lane = tid & 63;
    const int w    = tid >> 6;
    const int b    = blockIdx.x * WPB + w;   // 0..8191
    const int k    = lane & 7;               // GT index (x8 redundant)

    const float* pb_base = preds + (size_t)b * CELLS * ROW;

    // ---- issue independent loads first: conf baseline, gt box, gt label ----
    const float conf0 = pb_base[(size_t)(lane >> 1) * ROW + 4 + 5 * (lane & 1)];
    float conf1 = 0.0f;
    const int idx1 = lane + 64;
    if (idx1 < 98)
        conf1 = pb_base[(size_t)(idx1 >> 1) * ROW + 4 + 5 * (idx1 & 1)];

    const float4 gb = *(const float4*)(gtb + ((size_t)b * NGT + k) * 4);
    const int label = gtl[(size_t)b * NGT + k];

    // ---- geometry (depends only on gtb) ----
    const float x1 = gb.x, y1 = gb.y, x2 = gb.z, y2 = gb.w;
    const float gcx = (x1 + x2) * 0.5f, gcy = (y1 + y2) * 0.5f;
    const float gw = x2 - x1, gh = y2 - y1;
    int gi = (int)(gcx * 7.0f); gi = gi < 0 ? 0 : (gi > 6 ? 6 : gi);
    int gj = (int)(gcy * 7.0f); gj = gj < 0 ? 0 : (gj > 6 ? 6 : gj);
    const int cell = gj * 7 + gi;

    // ---- issue pred-cell loads (own k's cell) ----
    const float* pc = pb_base + (size_t)cell * ROW;   // 8B aligned (ROW even)
    float p[10];
    #pragma unroll
    for (int i = 0; i < 5; ++i) {
        float2 q = *(const float2*)(pc + 2 * i);
        p[2*i] = q.x; p[2*i+1] = q.y;
    }

    // ---- broadcast cells; issue class-row loads (overlap with pc loads) ----
    int cells[8], labels[8];
    #pragma unroll
    for (int j = 0; j < 8; ++j) {
        cells[j]  = __shfl(cell,  j, 64);
        labels[j] = __shfl(label, j, 64);
    }
    const int g = lane >> 3, sub = lane & 7;
    const float* pcl = pb_base + (size_t)cells[g] * ROW + 10;
    float clsv[10];
    #pragma unroll
    for (int t = 0; t < 10; ++t) clsv[t] = pcl[sub + (t << 3)];  // 0..79 once

    // ---- iou / best / targets (consumes pc) ----
    float ious[2];
    #pragma unroll
    for (int bb = 0; bb < 2; ++bb) {
        float pcx = (p[bb*5+0] + (float)gi) / 7.0f;
        float pcy = (p[bb*5+1] + (float)gj) / 7.0f;
        float pw  = p[bb*5+2] * p[bb*5+2];
        float ph  = p[bb*5+3] * p[bb*5+3];
        float bx1 = pcx - pw * 0.5f, by1 = pcy - ph * 0.5f;
        float bx2 = pcx + pw * 0.5f, by2 = pcy + ph * 0.5f;
        float ix1 = fmaxf(bx1, x1), iy1 = fmaxf(by1, y1);
        float ix2 = fminf(bx2, x2), iy2 = fminf(by2, y2);
        float inter = fmaxf(ix2 - ix1, 0.0f) * fmaxf(iy2 - iy1, 0.0f);
        float a1 = fmaxf(bx2 - bx1, 0.0f) * fmaxf(by2 - by1, 0.0f);
        float a2 = fmaxf(x2 - x1, 0.0f) * fmaxf(y2 - y1, 0.0f);
        ious[bb] = inter / (a1 + a2 - inter + 1e-6f);
    }
    const int   best = (ious[1] > ious[0]) ? 1 : 0;   // first max wins
    const float iou  = ious[best];
    float cv[4] = { gcx * 7.0f - (float)gi, gcy * 7.0f - (float)gj,
                    sqrtf(gw), sqrtf(gh) };
    float pbx[5];
    #pragma unroll
    for (int f = 0; f < 5; ++f) pbx[f] = p[best*5 + f];

    // ---- scan semantics: last writer per slot, first occurrence per cell ----
    const int slot = cell * 2 + best;
    int slots[8];
    #pragma unroll
    for (int j = 0; j < 8; ++j) slots[j] = __shfl(slot, j, 64);
    int fin = 1, rep = 1;
    uint32_t m0 = 0, m1 = 0, m2 = 0;
    #pragma unroll
    for (int j = 0; j < 8; ++j) {
        if (j > k && slots[j] == slot) fin = 0;
        if (j < k && cells[j] == cell) rep = 0;
        if (cells[j] == cell) {
            int l = labels[j];
            if (l < 32)      m0 |= 1u << l;
            else if (l < 64) m1 |= 1u << (l - 32);
            else             m2 |= 1u << (l - 64);
        }
    }

    // ---- accumulate ----
    float acc = 0.5f * conf0 * conf0 + 0.5f * conf1 * conf1;

    if (lane < 8 && fin) {   // slot corrections (lane k holds GT k directly)
        float c = 0.0f;
        #pragma unroll
        for (int f = 0; f < 4; ++f) { float d = pbx[f] - cv[f]; c += d * d; }
        acc += 5.0f * c;
        float d = pbx[4] - iou;
        acc += d * d - 0.5f * pbx[4] * pbx[4];
    }

    {   // class corrections for group g's cell, gated on rep_g
        const int      rep_g = __shfl(rep, g, 64);
        const uint32_t g0 = __shfl(m0, g, 64);
        const uint32_t g1 = __shfl(m1, g, 64);
        const uint32_t g2 = __shfl(m2, g, 64);
        if (rep_g) {
            #pragma unroll
            for (int t = 0; t < 10; ++t) {
                int c = sub + (t << 3);
                uint32_t bit = (c < 32) ? (g0 >> c)
                             : (c < 64) ? (g1 >> (c - 32))
                                        : (g2 >> (c - 64));
                float tv = (bit & 1u) ? 1.0f : 0.0f;
                float d = clsv[t] - tv;
                acc += d * d;
            }
        }
    }

    // ---- wave reduce, block combine via LDS ----
    #pragma unroll
    for (int off = 32; off > 0; off >>= 1)
        acc += __shfl_down(acc, off, 64);
    if (lane == 0) s_red[w] = acc;
    __syncthreads();

    // ---- last-block-done: publish partial, count arrivals ----
    if (tid == 0) {
        float t = s_red[0] + s_red[1] + s_red[2] + s_red[3];
        // device-scope atomic store -> visible at coherence point (cross-XCD)
        __hip_atomic_store(&partial[blockIdx.x], t,
                           __ATOMIC_RELAXED, __HIP_MEMORY_SCOPE_AGENT);
        __threadfence();   // release: partial store ordered before counter add
        unsigned int old = __hip_atomic_fetch_add(counter, 1u,
                           __ATOMIC_ACQ_REL, __HIP_MEMORY_SCOPE_AGENT);
        s_last = (old - POISON == (unsigned)(GRID - 1)) ? 1 : 0;
    }
    __syncthreads();

    // ---- the last-arriving block reduces all partials and writes out ----
    if (s_last) {
        float s = 0.0f;
        #pragma unroll
        for (int i = 0; i < GRID / BLOCK; ++i)   // 2048/256 = 8
            s += __hip_atomic_load(&partial[tid + i * BLOCK],
                                   __ATOMIC_RELAXED, __HIP_MEMORY_SCOPE_AGENT);
        #pragma unroll
        for (int off = 32; off > 0; off >>= 1)
            s += __shfl_down(s, off, 64);
        if (lane == 0) s_red[w] = s;
        __syncthreads();
        if (tid == 0) {
            float t = 0.0f;
            #pragma unroll
            for (int i = 0; i < WPB; ++i) t += s_red[i];
            out[0] = t;
        }
    }
}

extern "C" void kernel_launch(void* const* d_in, const int* in_sizes, int n_in,
                              void* d_out, int out_size, void* d_ws, size_t ws_size,
                              hipStream_t stream) {
    const float* preds = (const float*)d_in[0];
    const float* gtb   = (const float*)d_in[1];
    const int*   gtl   = (const int*)d_in[2];
    float*        partial = (float*)d_ws;                 // GRID floats
    unsigned int* counter = (unsigned int*)d_ws + GRID;   // 1 uint32, poison-init
    float* out = (float*)d_out;

    yolo_fused<<<GRID, BLOCK, 0, stream>>>(preds, gtb, gtl, partial, counter, out);
}

// Round 5
// 195.611 us; speedup vs baseline: 1.6232x; 1.6232x over previous
//
#include <hip/hip_runtime.h>
#include <cstdint>

#define BSZ   8192
#define NGT   8
#define ROW   90     // B*5 + C
#define CELLS 49     // 7*7
#define BLOCK 256
#define WPB   4      // waves per block
#define GRID  (BSZ / WPB)   // 2048 blocks, one batch item per wave

// Wave-per-batch main kernel (R3 structure — two-kernel; the single-kernel
// last-block-done variant regressed 124us: device-scope fences on gfx950
// serialize on per-XCD L2 writebacks). All 64 lanes compute phases A/B
// redundantly (k = lane&7) so cross-lane exchange is pure __shfl. Memory
// schedule: independent conf-baseline loads issued first; class-row float2
// loads issued as soon as cell geometry is known (independent of the
// pred-cell loads) -> 2 dependent memory rounds.
__launch_bounds__(BLOCK, 8)
__global__ void yolo_main(const float* __restrict__ preds,
                          const float* __restrict__ gtb,
                          const int*   __restrict__ gtl,
                          float* __restrict__ partial)
{
    __shared__ float s_red[WPB];
    const int tid  = threadIdx.x;
    const int lane = tid & 63;
    const int w    = tid >> 6;
    const int b    = blockIdx.x * WPB + w;   // 0..8191
    const int k    = lane & 7;               // GT index (x8 redundant)

    const float* pb_base = preds + (size_t)b * CELLS * ROW;

    // ---- issue independent loads first: conf baseline, gt box, gt label ----
    const float conf0 = pb_base[(size_t)(lane >> 1) * ROW + 4 + 5 * (lane & 1)];
    float conf1 = 0.0f;
    const int idx1 = lane + 64;
    if (idx1 < 98)
        conf1 = pb_base[(size_t)(idx1 >> 1) * ROW + 4 + 5 * (idx1 & 1)];

    const float4 gb = *(const float4*)(gtb + ((size_t)b * NGT + k) * 4);
    const int label = gtl[(size_t)b * NGT + k];

    // ---- geometry (depends only on gtb) ----
    const float x1 = gb.x, y1 = gb.y, x2 = gb.z, y2 = gb.w;
    const float gcx = (x1 + x2) * 0.5f, gcy = (y1 + y2) * 0.5f;
    const float gw = x2 - x1, gh = y2 - y1;
    int gi = (int)(gcx * 7.0f); gi = gi < 0 ? 0 : (gi > 6 ? 6 : gi);
    int gj = (int)(gcy * 7.0f); gj = gj < 0 ? 0 : (gj > 6 ? 6 : gj);
    const int cell = gj * 7 + gi;

    // ---- issue pred-cell loads (own k's cell) ----
    const float* pc = pb_base + (size_t)cell * ROW;   // 8B aligned (ROW even)
    float p[10];
    #pragma unroll
    for (int i = 0; i < 5; ++i) {
        float2 q = *(const float2*)(pc + 2 * i);
        p[2*i] = q.x; p[2*i+1] = q.y;
    }

    // ---- broadcast cells; issue class-row float2 loads (overlap with pc) ----
    int cells[8], labels[8];
    #pragma unroll
    for (int j = 0; j < 8; ++j) {
        cells[j]  = __shfl(cell,  j, 64);
        labels[j] = __shfl(label, j, 64);
    }
    const int g = lane >> 3, sub = lane & 7;
    // class channels 10..89: 8B-aligned base; lane sub covers pairs
    // {sub*2 + 16t, +1} for t=0..4 -> all 80 channels exactly once.
    const float* pcl = pb_base + (size_t)cells[g] * ROW + 10;
    float2 clsv[5];
    #pragma unroll
    for (int t = 0; t < 5; ++t)
        clsv[t] = *(const float2*)(pcl + sub * 2 + 16 * t);

    // ---- iou / best / targets (consumes pc) ----
    float ious[2];
    #pragma unroll
    for (int bb = 0; bb < 2; ++bb) {
        float pcx = (p[bb*5+0] + (float)gi) / 7.0f;
        float pcy = (p[bb*5+1] + (float)gj) / 7.0f;
        float pw  = p[bb*5+2] * p[bb*5+2];
        float ph  = p[bb*5+3] * p[bb*5+3];
        float bx1 = pcx - pw * 0.5f, by1 = pcy - ph * 0.5f;
        float bx2 = pcx + pw * 0.5f, by2 = pcy + ph * 0.5f;
        float ix1 = fmaxf(bx1, x1), iy1 = fmaxf(by1, y1);
        float ix2 = fminf(bx2, x2), iy2 = fminf(by2, y2);
        float inter = fmaxf(ix2 - ix1, 0.0f) * fmaxf(iy2 - iy1, 0.0f);
        float a1 = fmaxf(bx2 - bx1, 0.0f) * fmaxf(by2 - by1, 0.0f);
        float a2 = fmaxf(x2 - x1, 0.0f) * fmaxf(y2 - y1, 0.0f);
        ious[bb] = inter / (a1 + a2 - inter + 1e-6f);
    }
    const int   best = (ious[1] > ious[0]) ? 1 : 0;   // first max wins
    const float iou  = ious[best];
    float cv[4] = { gcx * 7.0f - (float)gi, gcy * 7.0f - (float)gj,
                    sqrtf(gw), sqrtf(gh) };
    float pbx[5];
    #pragma unroll
    for (int f = 0; f < 5; ++f) pbx[f] = p[best*5 + f];

    // ---- scan semantics: last writer per slot, first occurrence per cell ----
    const int slot = cell * 2 + best;
    int slots[8];
    #pragma unroll
    for (int j = 0; j < 8; ++j) slots[j] = __shfl(slot, j, 64);
    int fin = 1, rep = 1;
    uint32_t m0 = 0, m1 = 0, m2 = 0;
    #pragma unroll
    for (int j = 0; j < 8; ++j) {
        if (j > k && slots[j] == slot) fin = 0;
        if (j < k && cells[j] == cell) rep = 0;
        if (cells[j] == cell) {
            int l = labels[j];
            if (l < 32)      m0 |= 1u << l;
            else if (l < 64) m1 |= 1u << (l - 32);
            else             m2 |= 1u << (l - 64);
        }
    }

    // ---- accumulate ----
    float acc = 0.5f * conf0 * conf0 + 0.5f * conf1 * conf1;

    if (lane < 8 && fin) {   // slot corrections (lane k holds GT k directly)
        float c = 0.0f;
        #pragma unroll
        for (int f = 0; f < 4; ++f) { float d = pbx[f] - cv[f]; c += d * d; }
        acc += 5.0f * c;
        float d = pbx[4] - iou;
        acc += d * d - 0.5f * pbx[4] * pbx[4];
    }

    {   // class corrections for group g's cell, gated on rep_g
        const int      rep_g = __shfl(rep, g, 64);
        const uint32_t g0 = __shfl(m0, g, 64);
        const uint32_t g1 = __shfl(m1, g, 64);
        const uint32_t g2 = __shfl(m2, g, 64);
        if (rep_g) {
            #pragma unroll
            for (int t = 0; t < 5; ++t) {
                int c0 = sub * 2 + 16 * t;           // even channel
                int c1 = c0 + 1;                     // odd channel
                uint32_t bit0 = (c0 < 32) ? (g0 >> c0)
                              : (c0 < 64) ? (g1 >> (c0 - 32))
                                          : (g2 >> (c0 - 64));
                uint32_t bit1 = (c1 < 32) ? (g0 >> c1)
                              : (c1 < 64) ? (g1 >> (c1 - 32))
                                          : (g2 >> (c1 - 64));
                float d0 = clsv[t].x - ((bit0 & 1u) ? 1.0f : 0.0f);
                float d1 = clsv[t].y - ((bit1 & 1u) ? 1.0f : 0.0f);
                acc += d0 * d0 + d1 * d1;
            }
        }
    }

    // ---- wave reduce, block combine via LDS, one store per block ----
    #pragma unroll
    for (int off = 32; off > 0; off >>= 1)
        acc += __shfl_down(acc, off, 64);
    if (lane == 0) s_red[w] = acc;
    __syncthreads();
    if (tid == 0) {
        float t = 0.0f;
        #pragma unroll
        for (int i = 0; i < WPB; ++i) t += s_red[i];
        partial[blockIdx.x] = t;
    }
}

__global__ void yolo_reduce(const float* __restrict__ partial,
                            float* __restrict__ out)
{
    __shared__ float red[BLOCK / 64];
    const int tid = threadIdx.x, lane = tid & 63;
    float s = 0.0f;
    #pragma unroll
    for (int i = 0; i < GRID / (BLOCK * 4); ++i) {   // 2048/(256*4) = 2
        float4 v = *(const float4*)(partial + 4 * (tid + i * BLOCK));
        s += v.x + v.y + v.z + v.w;
    }
    #pragma unroll
    for (int off = 32; off > 0; off >>= 1)
        s += __shfl_down(s, off, 64);
    if (lane == 0) red[tid >> 6] = s;
    __syncthreads();
    if (tid == 0) {
        float t = 0.0f;
        #pragma unroll
        for (int i = 0; i < BLOCK / 64; ++i) t += red[i];
        out[0] = t;
    }
}

extern "C" void kernel_launch(void* const* d_in, const int* in_sizes, int n_in,
                              void* d_out, int out_size, void* d_ws, size_t ws_size,
                              hipStream_t stream) {
    const float* preds = (const float*)d_in[0];
    const float* gtb   = (const float*)d_in[1];
    const int*   gtl   = (const int*)d_in[2];
    float* partial = (float*)d_ws;     // 2048 floats, fully overwritten each call
    float* out     = (float*)d_out;

    yolo_main<<<GRID, BLOCK, 0, stream>>>(preds, gtb, gtl, partial);
    yolo_reduce<<<1, BLOCK, 0, stream>>>(partial, out);
}